// Round 1
// baseline (127.497 us; speedup 1.0000x reference)
//
#include <hip/hip_runtime.h>
#include <math.h>

#define ROWLEN 8192
#define TPB 256

// exact floor(log2(x)) for normal positive x: exponent field - 127
__device__ __forceinline__ int floor_log2_pos(float x) {
  return (int)((__float_as_uint(x) >> 23) & 255u) - 127;
}
// 2^e for e in [-126, 127]
__device__ __forceinline__ float exp2i(int e) {
  return __uint_as_float((unsigned)(e + 127) << 23);
}

// fake-quantize one element: x is the original input element,
// c = 2^-shared_exp / m2 (exact power of 2), os = 2^shared_exp * m2.
__device__ __forceinline__ float qe(float x, float c, float os) {
  float v = x * c;               // A/scale, |v| < 8
  float av = fabsf(v);
  int pe = (av == 0.f) ? 0 : floor_log2_pos(av);
  if (pe < 0) pe = 0;            // min_exp = 0 for e2m1
  float o = v * exp2i(1 - pe);   // v / 2^pe * mscale(=2), exact
  o = copysignf(floorf(fabsf(o) + 0.5f), o);  // round half away from zero
  o = o * exp2i(pe - 1);         // back: /mscale * 2^pe, exact
  o = fminf(6.f, fmaxf(-6.f, o));             // clip to MAX_NORM
  return o * os;                 // * scale * m_nano2 (exact)
}

__global__ __launch_bounds__(TPB) void mxq_kernel(const float* __restrict__ in,
                                                  float* __restrict__ out) {
  const int row = blockIdx.x;
  const int t = threadIdx.x;
  const size_t base = (size_t)row * ROWLEN + (size_t)t * 32;
  const float4* g = reinterpret_cast<const float4*>(in + base);

  // each thread owns one 32-element MX block, in registers
  float4 a[8];
#pragma unroll
  for (int j = 0; j < 8; ++j) a[j] = g[j];

  float amax = 0.f;
#pragma unroll
  for (int j = 0; j < 8; ++j) {
    amax = fmaxf(amax, fmaxf(fmaxf(fabsf(a[j].x), fabsf(a[j].y)),
                             fmaxf(fabsf(a[j].z), fabsf(a[j].w))));
  }

  // ---- row max (wave shuffle reduce + LDS across 4 waves) ----
  float rmax = amax;
#pragma unroll
  for (int m = 1; m < 64; m <<= 1)
    rmax = fmaxf(rmax, __shfl_xor(rmax, m, 64));
  __shared__ float smax[TPB / 64];
  if ((t & 63) == 0) smax[t >> 6] = rmax;
  __syncthreads();
  rmax = fmaxf(fmaxf(smax[0], smax[1]), fmaxf(smax[2], smax[3]));

  // ---- nano pre-scale: m2 in {1,2} ----
  float m2 = 1.f, inv_m2 = 1.f;
  if (rmax > 0.f) {
    int em = floor_log2_pos(rmax);
    float mn = rmax * exp2i(-em);          // mantissa in [1,2), exact
    mn = floorf(mn * 2.f + 0.5f) * 0.5f;   // {1, 1.5, 2}
    m2 = floorf(mn + 0.5f);                // {1, 2}
    inv_m2 = (m2 == 2.f) ? 0.5f : 1.f;
  }

  // ---- MX block shared exponent (on A = x/m2; amax scales exactly) ----
  float bmax = amax * inv_m2;
  int se = (bmax == 0.f) ? -2 : (floor_log2_pos(bmax) - 2);  // EMAX = 2
  if (se < -127) se = -127;
  const float c = exp2i(-se) * inv_m2;   // combined inverse scale (exact pow2)
  const float os = ldexpf(m2, se);       // scale * m2 (exact pow2)

  float4 r[8];
#pragma unroll
  for (int j = 0; j < 8; ++j) {
    r[j].x = qe(a[j].x, c, os);
    r[j].y = qe(a[j].y, c, os);
    r[j].z = qe(a[j].z, c, os);
    r[j].w = qe(a[j].w, c, os);
  }

  float4* o4 = reinterpret_cast<float4*>(out + base);
#pragma unroll
  for (int j = 0; j < 8; ++j) o4[j] = r[j];
}

extern "C" void kernel_launch(void* const* d_in, const int* in_sizes, int n_in,
                              void* d_out, int out_size, void* d_ws, size_t ws_size,
                              hipStream_t stream) {
  const float* in = (const float*)d_in[0];
  float* out = (float*)d_out;
  const int rows = in_sizes[0] / ROWLEN;   // 8192
  mxq_kernel<<<dim3(rows), dim3(TPB), 0, stream>>>(in, out);
}

// Round 2
// 90.967 us; speedup vs baseline: 1.4016x; 1.4016x over previous
//
#include <hip/hip_runtime.h>
#include <math.h>

#define ROWLEN 8192
#define TPB 256
#define J 8   // chunks per thread: ROWLEN / (TPB*4)

typedef float f32x4 __attribute__((ext_vector_type(4)));

// exact floor(log2(x)) for normal positive x: exponent field - 127
__device__ __forceinline__ int floor_log2_pos(float x) {
  return (int)((__float_as_uint(x) >> 23) & 255u) - 127;
}
// 2^e for e in [-126, 127]
__device__ __forceinline__ float exp2i(int e) {
  return __uint_as_float((unsigned)(e + 127) << 23);
}

// fake-quantize one element: x = original input element,
// c = 2^-shared_exp / m2 (exact pow2), os = 2^shared_exp * m2 (exact pow2).
__device__ __forceinline__ float qe(float x, float c, float os) {
  float v = x * c;               // A/scale, |v| < 8
  float av = fabsf(v);
  int pe = (av == 0.f) ? 0 : floor_log2_pos(av);
  if (pe < 0) pe = 0;            // min_exp = 0 for e2m1
  float o = v * exp2i(1 - pe);   // v / 2^pe * mscale(=2), exact
  o = copysignf(floorf(fabsf(o) + 0.5f), o);  // round half away from zero
  o = o * exp2i(pe - 1);         // back: /mscale * 2^pe, exact
  o = fminf(6.f, fmaxf(-6.f, o));             // clip to MAX_NORM
  return o * os;                 // * scale * m_nano2 (exact)
}

__global__ __launch_bounds__(TPB) void mxq_kernel(const float* __restrict__ in,
                                                  float* __restrict__ out) {
  const int row = blockIdx.x;
  const int t = threadIdx.x;
  const size_t base = (size_t)row * ROWLEN + (size_t)t * 4;

  // fully coalesced: wave-load j covers a contiguous 1 KB span.
  // lanes 8k..8k+7 of chunk j together hold one 32-element MX block.
  f32x4 a[J];
#pragma unroll
  for (int j = 0; j < J; ++j)
    a[j] = __builtin_nontemporal_load(
        reinterpret_cast<const f32x4*>(in + base + (size_t)j * (TPB * 4)));

  // per-chunk MX-block amax: max over own 4 elems, then across 8-lane group
  float bmax[J];
#pragma unroll
  for (int j = 0; j < J; ++j) {
    float m = fmaxf(fmaxf(fabsf(a[j].x), fabsf(a[j].y)),
                    fmaxf(fabsf(a[j].z), fabsf(a[j].w)));
    m = fmaxf(m, __shfl_xor(m, 1, 64));
    m = fmaxf(m, __shfl_xor(m, 2, 64));
    m = fmaxf(m, __shfl_xor(m, 4, 64));
    bmax[j] = m;
  }

  // ---- row max: combine chunks, wave reduce (xor 8/16/32), LDS across waves
  float rmax = bmax[0];
#pragma unroll
  for (int j = 1; j < J; ++j) rmax = fmaxf(rmax, bmax[j]);
  rmax = fmaxf(rmax, __shfl_xor(rmax, 8, 64));
  rmax = fmaxf(rmax, __shfl_xor(rmax, 16, 64));
  rmax = fmaxf(rmax, __shfl_xor(rmax, 32, 64));
  __shared__ float smax[TPB / 64];
  if ((t & 63) == 0) smax[t >> 6] = rmax;
  __syncthreads();
  rmax = fmaxf(fmaxf(smax[0], smax[1]), fmaxf(smax[2], smax[3]));

  // ---- nano pre-scale: m2 in {1,2} ----
  float m2 = 1.f, inv_m2 = 1.f;
  if (rmax > 0.f) {
    int em = floor_log2_pos(rmax);
    float mn = rmax * exp2i(-em);          // mantissa in [1,2), exact
    mn = floorf(mn * 2.f + 0.5f) * 0.5f;   // {1, 1.5, 2}
    m2 = floorf(mn + 0.5f);                // {1, 2}
    inv_m2 = (m2 == 2.f) ? 0.5f : 1.f;
  }

  // ---- per-chunk quantize + coalesced store ----
#pragma unroll
  for (int j = 0; j < J; ++j) {
    float bm = bmax[j] * inv_m2;
    int se = (bm == 0.f) ? -2 : (floor_log2_pos(bm) - 2);  // EMAX = 2
    if (se < -127) se = -127;
    const float c = exp2i(-se) * inv_m2;   // combined inverse scale (pow2)
    const float os = ldexpf(m2, se);       // scale * m_nano2 (pow2)

    f32x4 r;
    r.x = qe(a[j].x, c, os);
    r.y = qe(a[j].y, c, os);
    r.z = qe(a[j].z, c, os);
    r.w = qe(a[j].w, c, os);
    __builtin_nontemporal_store(
        r, reinterpret_cast<f32x4*>(out + base + (size_t)j * (TPB * 4)));
  }
}

extern "C" void kernel_launch(void* const* d_in, const int* in_sizes, int n_in,
                              void* d_out, int out_size, void* d_ws, size_t ws_size,
                              hipStream_t stream) {
  const float* in = (const float*)d_in[0];
  float* out = (float*)d_out;
  const int rows = in_sizes[0] / ROWLEN;   // 8192
  mxq_kernel<<<dim3(rows), dim3(TPB), 0, stream>>>(in, out);
}

// Round 3
// 89.936 us; speedup vs baseline: 1.4176x; 1.0115x over previous
//
#include <hip/hip_runtime.h>
#include <math.h>

#define ROWLEN 8192
#define TPB 512
#define J 4   // chunks per thread: ROWLEN / (TPB*4)

typedef float f32x4 __attribute__((ext_vector_type(4)));

// exact floor(log2(x)) for normal positive x: exponent field - 127
__device__ __forceinline__ int floor_log2_pos(float x) {
  return (int)((__float_as_uint(x) >> 23) & 255u) - 127;
}
// 2^e for e in [-126, 127]
__device__ __forceinline__ float exp2i(int e) {
  return __uint_as_float((unsigned)(e + 127) << 23);
}

// fake-quantize one element: x = original input element,
// c = 2^-shared_exp / m2 (exact pow2), os = 2^shared_exp * m2 (exact pow2).
__device__ __forceinline__ float qe(float x, float c, float os) {
  float v = x * c;               // A/scale, |v| < 8
  float av = fabsf(v);
  int pe = (av == 0.f) ? 0 : floor_log2_pos(av);
  if (pe < 0) pe = 0;            // min_exp = 0 for e2m1
  float o = v * exp2i(1 - pe);   // v / 2^pe * mscale(=2), exact
  o = copysignf(floorf(fabsf(o) + 0.5f), o);  // round half away from zero
  o = o * exp2i(pe - 1);         // back: /mscale * 2^pe, exact
  o = fminf(6.f, fmaxf(-6.f, o));             // clip to MAX_NORM
  return o * os;                 // * scale * m_nano2 (exact)
}

__global__ __launch_bounds__(TPB) void mxq_kernel(const float* __restrict__ in,
                                                  float* __restrict__ out) {
  const int row = blockIdx.x;
  const int t = threadIdx.x;
  const size_t base = (size_t)row * ROWLEN + (size_t)t * 4;

  // fully coalesced: wave-load j covers a contiguous 1 KB span.
  // lanes 8k..8k+7 of chunk j together hold one 32-element MX block.
  f32x4 a[J];
#pragma unroll
  for (int j = 0; j < J; ++j)
    a[j] = __builtin_nontemporal_load(
        reinterpret_cast<const f32x4*>(in + base + (size_t)j * (TPB * 4)));

  // per-chunk MX-block amax: max over own 4 elems, then across 8-lane group
  float bmax[J];
#pragma unroll
  for (int j = 0; j < J; ++j) {
    float m = fmaxf(fmaxf(fabsf(a[j].x), fabsf(a[j].y)),
                    fmaxf(fabsf(a[j].z), fabsf(a[j].w)));
    m = fmaxf(m, __shfl_xor(m, 1, 64));
    m = fmaxf(m, __shfl_xor(m, 2, 64));
    m = fmaxf(m, __shfl_xor(m, 4, 64));
    bmax[j] = m;
  }

  // ---- row max: combine chunks, wave reduce (xor 8/16/32), LDS across waves
  float rmax = bmax[0];
#pragma unroll
  for (int j = 1; j < J; ++j) rmax = fmaxf(rmax, bmax[j]);
  rmax = fmaxf(rmax, __shfl_xor(rmax, 8, 64));
  rmax = fmaxf(rmax, __shfl_xor(rmax, 16, 64));
  rmax = fmaxf(rmax, __shfl_xor(rmax, 32, 64));
  __shared__ float smax[TPB / 64];
  if ((t & 63) == 0) smax[t >> 6] = rmax;
  __syncthreads();
  rmax = smax[0];
#pragma unroll
  for (int w = 1; w < TPB / 64; ++w) rmax = fmaxf(rmax, smax[w]);

  // ---- nano pre-scale: m2 in {1,2} ----
  float m2 = 1.f, inv_m2 = 1.f;
  if (rmax > 0.f) {
    int em = floor_log2_pos(rmax);
    float mn = rmax * exp2i(-em);          // mantissa in [1,2), exact
    mn = floorf(mn * 2.f + 0.5f) * 0.5f;   // {1, 1.5, 2}
    m2 = floorf(mn + 0.5f);                // {1, 2}
    inv_m2 = (m2 == 2.f) ? 0.5f : 1.f;
  }

  // ---- per-chunk quantize + coalesced store ----
#pragma unroll
  for (int j = 0; j < J; ++j) {
    float bm = bmax[j] * inv_m2;
    int se = (bm == 0.f) ? -2 : (floor_log2_pos(bm) - 2);  // EMAX = 2
    if (se < -127) se = -127;
    const float c = exp2i(-se) * inv_m2;   // combined inverse scale (pow2)
    const float os = ldexpf(m2, se);       // scale * m_nano2 (pow2)

    f32x4 r;
    r.x = qe(a[j].x, c, os);
    r.y = qe(a[j].y, c, os);
    r.z = qe(a[j].z, c, os);
    r.w = qe(a[j].w, c, os);
    __builtin_nontemporal_store(
        r, reinterpret_cast<f32x4*>(out + base + (size_t)j * (TPB * 4)));
  }
}

extern "C" void kernel_launch(void* const* d_in, const int* in_sizes, int n_in,
                              void* d_out, int out_size, void* d_ws, size_t ws_size,
                              hipStream_t stream) {
  const float* in = (const float*)d_in[0];
  float* out = (float*)d_out;
  const int rows = in_sizes[0] / ROWLEN;   // 8192
  mxq_kernel<<<dim3(rows), dim3(TPB), 0, stream>>>(in, out);
}